// Round 7
// baseline (142.932 us; speedup 1.0000x reference)
//
#include <hip/hip_runtime.h>
#include <hip/hip_bf16.h>
#include <math.h>

// GAT forward, N=4096, FIN=128, H=4, FOUT=64.  All inputs f32, output f32.
//
// Round 17: SCAN AMPLIFICATION DIAGNOSTIC.  R16 (perfectly-coalesced scan)
// was null vs R14 (strided scan) -> request-coalescing theory dead; L2
// absorbs intra-wave fragmentation.  Remaining ambiguity: "scan ~24 us" is
// a RESIDUAL of the sum-model (fills 84 + k0 6 + k2 16.4), not a
// measurement; a hidden ~20-us input-restore copy inside the timed region
// (invisible below the 41-us fills in top-5) would mean the scan is
// actually cheap and five rounds of scan surgery were aimed at a ~5-us
// kernel.  This round: byte-identical to R16 but k_scan launched TWICE
// (idempotent).  dur - 131.4 == one true k_scan pass.
//   ~24 -> scan latency-capped: re-fuse scan into k2 (R12 form) next.
//   ~11 -> scan at HBM floor: attack k2 (16.4 measured vs ~6-8 floor).
//   ~3  -> hidden restore exists; budget nearly exhausted; attack k2.
//
// ws layout (bytes):
//   h2b     [N][H*FO] bf16   offset 0       (2 MB)
//   skip_ws [N][H*FO] f32    offset 2 MB    (4 MB)
//   src4    [N][4]    f32    offset 6 MB    (64 KB)
//   tgt4    [N][4]    f32    offset 6 MB+64K(64 KB)
//   bm      [N][256]  u16    offset 8 MB    (2 MB)

#define NN   4096
#define FIN  128
#define NH   4
#define FO   64
#define HF   256
#define LIST 192
#define GEMM_BLOCKS 512

typedef unsigned short ushort_t;
typedef unsigned int uint4n __attribute__((ext_vector_type(4)));

__device__ __forceinline__ ushort_t f2bf(float f) {
    __hip_bfloat16 h = __float2bfloat16(f);
    union { __hip_bfloat16 h; ushort_t u; } c; c.h = h; return c.u;
}
__device__ __forceinline__ float bf2f(ushort_t u) {
    union { unsigned int i; float f; } c; c.i = ((unsigned int)u) << 16; return c.f;
}

// ---------------------------------------------------------------------------
// k0_gemm: unchanged.
// ---------------------------------------------------------------------------
__global__ __launch_bounds__(256) void k0_gemm(
        const float* __restrict__ x,
        const float* __restrict__ proj,
        const float* __restrict__ skw,
        const float* __restrict__ asrc,
        const float* __restrict__ atgt,
        ushort_t* __restrict__ h2b, float* __restrict__ skip_ws,
        float* __restrict__ src4, float* __restrict__ tgt4) {
    __shared__ float sA[64 * 68];
    __shared__ float sB[64 * 64];
    const int tid = threadIdx.x;
    const int blk = blockIdx.x;

    const int bc = blk >> 6;
    const int i0 = (blk & 63) * 64;
    const int tx = tid & 15, ty = tid >> 4;
    const int r0 = ty << 2, c0 = tx << 2;
    float acc[4][4] = {};

    #pragma unroll
    for (int kb = 0; kb < FIN; kb += 64) {
        if (kb) __syncthreads();
        #pragma unroll
        for (int q = 0; q < 4; q++) {
            int s   = tid + q * 256;
            int row = s >> 4;
            int c4  = (s & 15) << 2;
            float4 v = *(const float4*)(x + (size_t)(i0 + row) * FIN + kb + c4);
            float* d = sA + row * 68 + c4;
            d[0] = v.x; d[1] = v.y; d[2] = v.z; d[3] = v.w;
        }
        if (bc < 4) {
            const float4* src = (const float4*)(proj + (size_t)bc * FIN * FO
                                                + (size_t)kb * FO);
            #pragma unroll
            for (int q = 0; q < 4; q++) {
                int s = tid + q * 256;
                *(float4*)(sB + (size_t)s * 4) = src[s];
            }
        } else {
            const float* sw = skw + (size_t)(bc - 4) * 64 * FIN;
            #pragma unroll
            for (int q = 0; q < 4; q++) {
                int s  = tid + q * 256;
                int c  = s & 63;
                int k4 = (s >> 6) << 2;
                float4 v = *(const float4*)(sw + (size_t)c * FIN + kb + k4);
                sB[(k4 + 0) * 64 + c] = v.x;
                sB[(k4 + 1) * 64 + c] = v.y;
                sB[(k4 + 2) * 64 + c] = v.z;
                sB[(k4 + 3) * 64 + c] = v.w;
            }
        }
        __syncthreads();

        #pragma unroll 2
        for (int k = 0; k < 64; k += 4) {
            alignas(16) float a[4][4];
            alignas(16) float b[4][4];
            #pragma unroll
            for (int rr = 0; rr < 4; rr++)
                *(float4*)a[rr] = *(const float4*)(sA + (r0 + rr) * 68 + k);
            #pragma unroll
            for (int kk = 0; kk < 4; kk++)
                *(float4*)b[kk] = *(const float4*)(sB + (k + kk) * 64 + c0);
            #pragma unroll
            for (int kk = 0; kk < 4; kk++)
                #pragma unroll
                for (int rr = 0; rr < 4; rr++)
                    #pragma unroll
                    for (int cc = 0; cc < 4; cc++)
                        acc[rr][cc] = fmaf(a[rr][kk], b[kk][cc], acc[rr][cc]);
        }
    }

    if (bc < 4) {
        #pragma unroll
        for (int rr = 0; rr < 4; rr++) {
            ushort4 hv;
            hv.x = f2bf(acc[rr][0]); hv.y = f2bf(acc[rr][1]);
            hv.z = f2bf(acc[rr][2]); hv.w = f2bf(acc[rr][3]);
            *(ushort4*)(h2b + (size_t)(i0 + r0 + rr) * HF + bc * 64 + c0) = hv;
        }
        float as[4], at[4];
        #pragma unroll
        for (int cc = 0; cc < 4; cc++) {
            as[cc] = asrc[bc * FO + c0 + cc];
            at[cc] = atgt[bc * FO + c0 + cc];
        }
        #pragma unroll
        for (int rr = 0; rr < 4; rr++) {
            float ps = acc[rr][0] * as[0] + acc[rr][1] * as[1]
                     + acc[rr][2] * as[2] + acc[rr][3] * as[3];
            float pt = acc[rr][0] * at[0] + acc[rr][1] * at[1]
                     + acc[rr][2] * at[2] + acc[rr][3] * at[3];
            #pragma unroll
            for (int off = 8; off >= 1; off >>= 1) {
                ps += __shfl_xor(ps, off, 64);
                pt += __shfl_xor(pt, off, 64);
            }
            if (tx == 0) {
                int i = i0 + r0 + rr;
                src4[(size_t)i * 4 + bc] = ps;
                tgt4[(size_t)i * 4 + bc] = pt;
            }
        }
    } else {
        float* dst = skip_ws + (size_t)i0 * HF + (bc - 4) * 64;
        #pragma unroll
        for (int rr = 0; rr < 4; rr++)
            *(float4*)(dst + (size_t)(r0 + rr) * HF + c0) = *(float4*)acc[rr];
    }
}

// ---------------------------------------------------------------------------
// k_scan: unchanged from R16.  Launched TWICE this round (idempotent).
// ---------------------------------------------------------------------------
__global__ __launch_bounds__(256) void k_scan(
        const unsigned int* __restrict__ mask,
        ushort_t* __restrict__ bm) {
    const int lane = threadIdx.x & 63, w = threadIdx.x >> 6;
    const int wid  = blockIdx.x * 4 + w;         // 0..8191
    const uint4n* mb = (const uint4n*)mask;

    const int sgA  = wid;                         // chunk A
    const int sgB  = wid + 8192;                  // chunk B
    const uint4n* pa = mb + (size_t)(sgA >> 2) * 1024 + (sgA & 3) * 256;
    const uint4n* pb = mb + (size_t)(sgB >> 2) * 1024 + (sgB & 3) * 256;

    uint4n va0 = pa[0 * 64 + lane], va1 = pa[1 * 64 + lane];
    uint4n va2 = pa[2 * 64 + lane], va3 = pa[3 * 64 + lane];
    uint4n vb0 = pb[0 * 64 + lane], vb1 = pb[1 * 64 + lane];
    uint4n vb2 = pb[2 * 64 + lane], vb3 = pb[3 * 64 + lane];

    unsigned ha = 0, hb = 0;
    #pragma unroll
    for (int e = 0; e < 4; e++) {
        ha |= ((va0[e] & 0x7fffffffu) == 0u ? 1u : 0u) << (0 * 4 + e);
        ha |= ((va1[e] & 0x7fffffffu) == 0u ? 1u : 0u) << (1 * 4 + e);
        ha |= ((va2[e] & 0x7fffffffu) == 0u ? 1u : 0u) << (2 * 4 + e);
        ha |= ((va3[e] & 0x7fffffffu) == 0u ? 1u : 0u) << (3 * 4 + e);
        hb |= ((vb0[e] & 0x7fffffffu) == 0u ? 1u : 0u) << (0 * 4 + e);
        hb |= ((vb1[e] & 0x7fffffffu) == 0u ? 1u : 0u) << (1 * 4 + e);
        hb |= ((vb2[e] & 0x7fffffffu) == 0u ? 1u : 0u) << (2 * 4 + e);
        hb |= ((vb3[e] & 0x7fffffffu) == 0u ? 1u : 0u) << (3 * 4 + e);
    }
    bm[(size_t)(sgA >> 2) * 256 + (sgA & 3) * 64 + lane] = (ushort_t)ha;
    bm[(size_t)(sgB >> 2) * 256 + (sgB & 3) * 64 + lane] = (ushort_t)hb;
}

// ---------------------------------------------------------------------------
// k2_attn: unchanged from R16.
// ---------------------------------------------------------------------------
struct K2Shared {
    int   s_j[LIST];
    float s_p[4][LIST + 1];
    float s_red[4][256];
    int   s_cnt[4];
    float s_inv[4];
};

__global__ __launch_bounds__(256) void k2_attn(
        const ushort_t* __restrict__ bm,
        const ushort_t* __restrict__ h2b,
        const float* __restrict__ skip_ws,
        const float* __restrict__ src4,
        const float* __restrict__ tgt4,
        const float* __restrict__ bias,
        float* __restrict__ out) {
    __shared__ K2Shared sh;
    const int tid  = threadIdx.x;
    const int lane = tid & 63, w = tid >> 6;
    const int i    = blockIdx.x;

    const unsigned hm = bm[(size_t)i * 256 + w * 64 + lane];
    const float skipv = skip_ws[(size_t)i * HF + tid];
    const float bv    = bias[tid];
    const float sc    = src4[(size_t)i * 4 + w];

    const int cl = __popc(hm);
    int incl = cl;
    #pragma unroll
    for (int o = 1; o < 64; o <<= 1) {
        int t = __shfl_up(incl, o, 64);
        if (lane >= o) incl += t;
    }
    const int excl = incl - cl;
    if (lane == 63) sh.s_cnt[w] = incl;
    __syncthreads();
    const int t0 = sh.s_cnt[0], t1 = sh.s_cnt[1],
              t2 = sh.s_cnt[2], t3 = sh.s_cnt[3];
    const int off = (w > 0 ? t0 : 0) + (w > 1 ? t1 : 0) + (w > 2 ? t2 : 0);
    int c = t0 + t1 + t2 + t3;
    c = c < LIST ? c : LIST;

    {
        int p = off + excl;
        unsigned mm = hm;
        while (mm) {
            int b = __builtin_ctz(mm);
            mm &= mm - 1;
            if (p < LIST)
                sh.s_j[p] = (w << 10) + ((b >> 2) << 8) + (lane << 2) + (b & 3);
            p++;
        }
    }
    __syncthreads();

    float lsum = 0.f;
    for (int kk = lane; kk < c; kk += 64) {
        int j = sh.s_j[kk];
        float pv = sc + tgt4[(size_t)j * 4 + w];
        pv = pv > 0.f ? pv : 0.2f * pv;
        pv = __expf(pv);
        sh.s_p[w][kk] = pv;
        lsum += pv;
    }
    #pragma unroll
    for (int o = 32; o >= 1; o >>= 1)
        lsum += __shfl_xor(lsum, o, 64);
    if (lane == 0) sh.s_inv[w] = lsum > 0.f ? 1.0f / lsum : 0.0f;
    __syncthreads();

    const int h = lane >> 4;
    const ushort_t* hp = h2b + 4 * lane;
    float4 acc = {0.f, 0.f, 0.f, 0.f};
    int kk = w;
    for (; kk + 12 < c; kk += 16) {
        int   j0 = sh.s_j[kk],        j1 = sh.s_j[kk + 4];
        int   j2 = sh.s_j[kk + 8],    j3 = sh.s_j[kk + 12];
        float p0 = sh.s_p[h][kk],     p1 = sh.s_p[h][kk + 4];
        float p2 = sh.s_p[h][kk + 8], p3 = sh.s_p[h][kk + 12];
        ushort4 a0 = *(const ushort4*)(hp + (size_t)j0 * HF);
        ushort4 a1 = *(const ushort4*)(hp + (size_t)j1 * HF);
        ushort4 a2 = *(const ushort4*)(hp + (size_t)j2 * HF);
        ushort4 a3 = *(const ushort4*)(hp + (size_t)j3 * HF);
        acc.x = fmaf(p0, bf2f(a0.x), acc.x);
        acc.y = fmaf(p0, bf2f(a0.y), acc.y);
        acc.z = fmaf(p0, bf2f(a0.z), acc.z);
        acc.w = fmaf(p0, bf2f(a0.w), acc.w);
        acc.x = fmaf(p1, bf2f(a1.x), acc.x);
        acc.y = fmaf(p1, bf2f(a1.y), acc.y);
        acc.z = fmaf(p1, bf2f(a1.z), acc.z);
        acc.w = fmaf(p1, bf2f(a1.w), acc.w);
        acc.x = fmaf(p2, bf2f(a2.x), acc.x);
        acc.y = fmaf(p2, bf2f(a2.y), acc.y);
        acc.z = fmaf(p2, bf2f(a2.z), acc.z);
        acc.w = fmaf(p2, bf2f(a2.w), acc.w);
        acc.x = fmaf(p3, bf2f(a3.x), acc.x);
        acc.y = fmaf(p3, bf2f(a3.y), acc.y);
        acc.z = fmaf(p3, bf2f(a3.z), acc.z);
        acc.w = fmaf(p3, bf2f(a3.w), acc.w);
    }
    for (; kk < c; kk += 4) {
        int   j0 = sh.s_j[kk];
        float p0 = sh.s_p[h][kk];
        ushort4 a0 = *(const ushort4*)(hp + (size_t)j0 * HF);
        acc.x = fmaf(p0, bf2f(a0.x), acc.x);
        acc.y = fmaf(p0, bf2f(a0.y), acc.y);
        acc.z = fmaf(p0, bf2f(a0.z), acc.z);
        acc.w = fmaf(p0, bf2f(a0.w), acc.w);
    }
    *(float4*)&sh.s_red[w][4 * lane] = acc;
    __syncthreads();

    float tot = sh.s_red[0][tid] + sh.s_red[1][tid]
              + sh.s_red[2][tid] + sh.s_red[3][tid];
    float vv = tot * sh.s_inv[tid >> 6] + skipv + bv;
    vv = vv > 0.f ? vv : expm1f(vv);
    out[(size_t)i * HF + tid] = vv;
}

extern "C" void kernel_launch(void* const* d_in, const int* in_sizes, int n_in,
                              void* d_out, int out_size, void* d_ws, size_t ws_size,
                              hipStream_t stream) {
    const float*        x    = (const float*)d_in[0];
    const unsigned int* mask = (const unsigned int*)d_in[1];
    const float*        proj = (const float*)d_in[2];
    const float*        asrc = (const float*)d_in[3];
    const float*        atgt = (const float*)d_in[4];
    const float*        skw  = (const float*)d_in[5];
    const float*        bias = (const float*)d_in[6];
    float*              out  = (float*)d_out;

    char* ws = (char*)d_ws;
    ushort_t* h2b     = (ushort_t*)ws;                          // 2 MB
    float*    skip_ws = (float*)(ws + (2u << 20));              // 4 MB
    float*    src4    = (float*)(ws + (6u << 20));              // 64 KB
    float*    tgt4    = (float*)(ws + (6u << 20) + (64u << 10));// 64 KB
    ushort_t* bm      = (ushort_t*)(ws + (8u << 20));           // 2 MB

    hipLaunchKernelGGL(k0_gemm, dim3(GEMM_BLOCKS), dim3(256), 0, stream,
                       x, proj, skw, asrc, atgt,
                       h2b, skip_ws, src4, tgt4);
    // ---- DIAGNOSTIC: k_scan launched twice (idempotent).  dur delta vs
    //      R16's 131.4 == one true k_scan pass. ----
    hipLaunchKernelGGL(k_scan, dim3(2048), dim3(256), 0, stream,
                       mask, bm);
    hipLaunchKernelGGL(k_scan, dim3(2048), dim3(256), 0, stream,
                       mask, bm);
    hipLaunchKernelGGL(k2_attn, dim3(NN), dim3(256), 0, stream,
                       bm, h2b, skip_ws, src4, tgt4, bias, out);
}

// Round 8
// 129.143 us; speedup vs baseline: 1.1068x; 1.1068x over previous
//
#include <hip/hip_runtime.h>
#include <hip/hip_bf16.h>
#include <math.h>

// GAT forward, N=4096, FIN=128, H=4, FOUT=64.  All inputs f32, output f32.
//
// Round 18: overlap GEMM with the scan.  R17 closed the budget with
// measurements: scan = 11.5 us (5.6 TB/s, at stream floor), k2 = 16.4 us,
// k0 ~ 6 us serial, ~13.5 us of fixed unattributed harness cost (likely
// mask-restore + launch overhead), fills ~84.  The scan theories are dead;
// the remaining measured-backed lever is that k0_gemm and k_scan are fully
// independent (disjoint reads AND writes) yet serialized.  This round fuses
// them into ONE heterogeneous race-free kernel, interleaved 4:1 so GEMM
// blocks dispatch immediately: compute-bound GEMM (~6 us VALU) hides under
// the memory-bound mask stream (~11.5 us HBM).  Also saves one launch.
// k2_attn byte-identical (proven 16.4) for clean attribution.
//   blk % 5 == 4 -> GEMM block  (512 total), gemm_id = blk/5
//   else         -> scan block (2048 total), scan_id = (blk/5)*4 + blk%5
//
// ws layout (bytes):
//   h2b     [N][H*FO] bf16   offset 0       (2 MB)
//   skip_ws [N][H*FO] f32    offset 2 MB    (4 MB)
//   src4    [N][4]    f32    offset 6 MB    (64 KB)
//   tgt4    [N][4]    f32    offset 6 MB+64K(64 KB)
//   bm      [N][256]  u16    offset 8 MB    (2 MB)

#define NN   4096
#define FIN  128
#define NH   4
#define FO   64
#define HF   256
#define LIST 192
#define GEMM_BLOCKS 512
#define SCAN_BLOCKS 2048

typedef unsigned short ushort_t;
typedef unsigned int uint4n __attribute__((ext_vector_type(4)));

__device__ __forceinline__ ushort_t f2bf(float f) {
    __hip_bfloat16 h = __float2bfloat16(f);
    union { __hip_bfloat16 h; ushort_t u; } c; c.h = h; return c.u;
}
__device__ __forceinline__ float bf2f(ushort_t u) {
    union { unsigned int i; float f; } c; c.i = ((unsigned int)u) << 16; return c.f;
}

// ---------------------------------------------------------------------------
// k01_fused: heterogeneous GEMM || scan.  Disjoint inputs/outputs -> no
// cross-block dependency, race-free.  Scan blocks don't touch LDS (they
// inherit the 33.8-KB allocation -> 4 blocks/CU; scan BW measured
// insensitive to occupancy/addressing across R14-R17).
// ---------------------------------------------------------------------------
__global__ __launch_bounds__(256) void k01_fused(
        const float* __restrict__ x,      // [N][FIN]
        const float* __restrict__ proj,   // [H][FIN][FO]
        const float* __restrict__ skw,    // [HF][FIN]
        const float* __restrict__ asrc,   // [H][FO]
        const float* __restrict__ atgt,   // [H][FO]
        const unsigned int* __restrict__ mask,   // f32 bits [N][N]
        ushort_t* __restrict__ h2b, float* __restrict__ skip_ws,
        float* __restrict__ src4, float* __restrict__ tgt4,
        ushort_t* __restrict__ bm) {
    __shared__ float sA[64 * 68];
    __shared__ float sB[64 * 64];
    const int tid = threadIdx.x;
    const int blk = blockIdx.x;
    const int q5  = blk / 5, r5 = blk - q5 * 5;

    if (r5 != 4) {
        // ================= scan path (R16's coalesced k_scan) =============
        const int lane = tid & 63, w = tid >> 6;
        const int wid  = (q5 * 4 + r5) * 4 + w;   // 0..8191
        const uint4n* mb = (const uint4n*)mask;

        const int sgA  = wid;
        const int sgB  = wid + 8192;
        const uint4n* pa = mb + (size_t)(sgA >> 2) * 1024 + (sgA & 3) * 256;
        const uint4n* pb = mb + (size_t)(sgB >> 2) * 1024 + (sgB & 3) * 256;

        uint4n va0 = pa[0 * 64 + lane], va1 = pa[1 * 64 + lane];
        uint4n va2 = pa[2 * 64 + lane], va3 = pa[3 * 64 + lane];
        uint4n vb0 = pb[0 * 64 + lane], vb1 = pb[1 * 64 + lane];
        uint4n vb2 = pb[2 * 64 + lane], vb3 = pb[3 * 64 + lane];

        unsigned ha = 0, hb = 0;
        #pragma unroll
        for (int e = 0; e < 4; e++) {
            ha |= ((va0[e] & 0x7fffffffu) == 0u ? 1u : 0u) << (0 * 4 + e);
            ha |= ((va1[e] & 0x7fffffffu) == 0u ? 1u : 0u) << (1 * 4 + e);
            ha |= ((va2[e] & 0x7fffffffu) == 0u ? 1u : 0u) << (2 * 4 + e);
            ha |= ((va3[e] & 0x7fffffffu) == 0u ? 1u : 0u) << (3 * 4 + e);
            hb |= ((vb0[e] & 0x7fffffffu) == 0u ? 1u : 0u) << (0 * 4 + e);
            hb |= ((vb1[e] & 0x7fffffffu) == 0u ? 1u : 0u) << (1 * 4 + e);
            hb |= ((vb2[e] & 0x7fffffffu) == 0u ? 1u : 0u) << (2 * 4 + e);
            hb |= ((vb3[e] & 0x7fffffffu) == 0u ? 1u : 0u) << (3 * 4 + e);
        }
        bm[(size_t)(sgA >> 2) * 256 + (sgA & 3) * 64 + lane] = (ushort_t)ha;
        bm[(size_t)(sgB >> 2) * 256 + (sgB & 3) * 64 + lane] = (ushort_t)hb;
        return;
    }

    // ================= GEMM path (R16's k0_gemm, blk -> gemm_id) =========
    const int gb = q5;                  // 0..511
    const int bc = gb >> 6;             // 0..7
    const int i0 = (gb & 63) * 64;
    const int tx = tid & 15, ty = tid >> 4;
    const int r0 = ty << 2, c0 = tx << 2;
    float acc[4][4] = {};

    #pragma unroll
    for (int kb = 0; kb < FIN; kb += 64) {
        if (kb) __syncthreads();
        #pragma unroll
        for (int q = 0; q < 4; q++) {
            int s   = tid + q * 256;
            int row = s >> 4;
            int c4  = (s & 15) << 2;
            float4 v = *(const float4*)(x + (size_t)(i0 + row) * FIN + kb + c4);
            float* d = sA + row * 68 + c4;
            d[0] = v.x; d[1] = v.y; d[2] = v.z; d[3] = v.w;
        }
        if (bc < 4) {
            const float4* src = (const float4*)(proj + (size_t)bc * FIN * FO
                                                + (size_t)kb * FO);
            #pragma unroll
            for (int q = 0; q < 4; q++) {
                int s = tid + q * 256;
                *(float4*)(sB + (size_t)s * 4) = src[s];
            }
        } else {
            const float* sw = skw + (size_t)(bc - 4) * 64 * FIN;
            #pragma unroll
            for (int q = 0; q < 4; q++) {
                int s  = tid + q * 256;
                int c  = s & 63;
                int k4 = (s >> 6) << 2;
                float4 v = *(const float4*)(sw + (size_t)c * FIN + kb + k4);
                sB[(k4 + 0) * 64 + c] = v.x;
                sB[(k4 + 1) * 64 + c] = v.y;
                sB[(k4 + 2) * 64 + c] = v.z;
                sB[(k4 + 3) * 64 + c] = v.w;
            }
        }
        __syncthreads();

        #pragma unroll 2
        for (int k = 0; k < 64; k += 4) {
            alignas(16) float a[4][4];
            alignas(16) float b[4][4];
            #pragma unroll
            for (int rr = 0; rr < 4; rr++)
                *(float4*)a[rr] = *(const float4*)(sA + (r0 + rr) * 68 + k);
            #pragma unroll
            for (int kk = 0; kk < 4; kk++)
                *(float4*)b[kk] = *(const float4*)(sB + (k + kk) * 64 + c0);
            #pragma unroll
            for (int kk = 0; kk < 4; kk++)
                #pragma unroll
                for (int rr = 0; rr < 4; rr++)
                    #pragma unroll
                    for (int cc = 0; cc < 4; cc++)
                        acc[rr][cc] = fmaf(a[rr][kk], b[kk][cc], acc[rr][cc]);
        }
    }

    if (bc < 4) {
        #pragma unroll
        for (int rr = 0; rr < 4; rr++) {
            ushort4 hv;
            hv.x = f2bf(acc[rr][0]); hv.y = f2bf(acc[rr][1]);
            hv.z = f2bf(acc[rr][2]); hv.w = f2bf(acc[rr][3]);
            *(ushort4*)(h2b + (size_t)(i0 + r0 + rr) * HF + bc * 64 + c0) = hv;
        }
        float as[4], at[4];
        #pragma unroll
        for (int cc = 0; cc < 4; cc++) {
            as[cc] = asrc[bc * FO + c0 + cc];
            at[cc] = atgt[bc * FO + c0 + cc];
        }
        #pragma unroll
        for (int rr = 0; rr < 4; rr++) {
            float ps = acc[rr][0] * as[0] + acc[rr][1] * as[1]
                     + acc[rr][2] * as[2] + acc[rr][3] * as[3];
            float pt = acc[rr][0] * at[0] + acc[rr][1] * at[1]
                     + acc[rr][2] * at[2] + acc[rr][3] * at[3];
            #pragma unroll
            for (int off = 8; off >= 1; off >>= 1) {
                ps += __shfl_xor(ps, off, 64);
                pt += __shfl_xor(pt, off, 64);
            }
            if (tx == 0) {
                int i = i0 + r0 + rr;
                src4[(size_t)i * 4 + bc] = ps;
                tgt4[(size_t)i * 4 + bc] = pt;
            }
        }
    } else {
        float* dst = skip_ws + (size_t)i0 * HF + (bc - 4) * 64;
        #pragma unroll
        for (int rr = 0; rr < 4; rr++)
            *(float4*)(dst + (size_t)(r0 + rr) * HF + c0) = *(float4*)acc[rr];
    }
}

// ---------------------------------------------------------------------------
// k2_attn: byte-identical to R16 (proven 16.4 us).
// ---------------------------------------------------------------------------
struct K2Shared {
    int   s_j[LIST];
    float s_p[4][LIST + 1];
    float s_red[4][256];
    int   s_cnt[4];
    float s_inv[4];
};

__global__ __launch_bounds__(256) void k2_attn(
        const ushort_t* __restrict__ bm,
        const ushort_t* __restrict__ h2b,
        const float* __restrict__ skip_ws,
        const float* __restrict__ src4,
        const float* __restrict__ tgt4,
        const float* __restrict__ bias,
        float* __restrict__ out) {
    __shared__ K2Shared sh;
    const int tid  = threadIdx.x;
    const int lane = tid & 63, w = tid >> 6;
    const int i    = blockIdx.x;

    const unsigned hm = bm[(size_t)i * 256 + w * 64 + lane];
    const float skipv = skip_ws[(size_t)i * HF + tid];
    const float bv    = bias[tid];
    const float sc    = src4[(size_t)i * 4 + w];

    const int cl = __popc(hm);
    int incl = cl;
    #pragma unroll
    for (int o = 1; o < 64; o <<= 1) {
        int t = __shfl_up(incl, o, 64);
        if (lane >= o) incl += t;
    }
    const int excl = incl - cl;
    if (lane == 63) sh.s_cnt[w] = incl;
    __syncthreads();
    const int t0 = sh.s_cnt[0], t1 = sh.s_cnt[1],
              t2 = sh.s_cnt[2], t3 = sh.s_cnt[3];
    const int off = (w > 0 ? t0 : 0) + (w > 1 ? t1 : 0) + (w > 2 ? t2 : 0);
    int c = t0 + t1 + t2 + t3;
    c = c < LIST ? c : LIST;

    {
        int p = off + excl;
        unsigned mm = hm;
        while (mm) {
            int b = __builtin_ctz(mm);
            mm &= mm - 1;
            if (p < LIST)
                sh.s_j[p] = (w << 10) + ((b >> 2) << 8) + (lane << 2) + (b & 3);
            p++;
        }
    }
    __syncthreads();

    float lsum = 0.f;
    for (int kk = lane; kk < c; kk += 64) {
        int j = sh.s_j[kk];
        float pv = sc + tgt4[(size_t)j * 4 + w];
        pv = pv > 0.f ? pv : 0.2f * pv;
        pv = __expf(pv);
        sh.s_p[w][kk] = pv;
        lsum += pv;
    }
    #pragma unroll
    for (int o = 32; o >= 1; o >>= 1)
        lsum += __shfl_xor(lsum, o, 64);
    if (lane == 0) sh.s_inv[w] = lsum > 0.f ? 1.0f / lsum : 0.0f;
    __syncthreads();

    const int h = lane >> 4;
    const ushort_t* hp = h2b + 4 * lane;
    float4 acc = {0.f, 0.f, 0.f, 0.f};
    int kk = w;
    for (; kk + 12 < c; kk += 16) {
        int   j0 = sh.s_j[kk],        j1 = sh.s_j[kk + 4];
        int   j2 = sh.s_j[kk + 8],    j3 = sh.s_j[kk + 12];
        float p0 = sh.s_p[h][kk],     p1 = sh.s_p[h][kk + 4];
        float p2 = sh.s_p[h][kk + 8], p3 = sh.s_p[h][kk + 12];
        ushort4 a0 = *(const ushort4*)(hp + (size_t)j0 * HF);
        ushort4 a1 = *(const ushort4*)(hp + (size_t)j1 * HF);
        ushort4 a2 = *(const ushort4*)(hp + (size_t)j2 * HF);
        ushort4 a3 = *(const ushort4*)(hp + (size_t)j3 * HF);
        acc.x = fmaf(p0, bf2f(a0.x), acc.x);
        acc.y = fmaf(p0, bf2f(a0.y), acc.y);
        acc.z = fmaf(p0, bf2f(a0.z), acc.z);
        acc.w = fmaf(p0, bf2f(a0.w), acc.w);
        acc.x = fmaf(p1, bf2f(a1.x), acc.x);
        acc.y = fmaf(p1, bf2f(a1.y), acc.y);
        acc.z = fmaf(p1, bf2f(a1.z), acc.z);
        acc.w = fmaf(p1, bf2f(a1.w), acc.w);
        acc.x = fmaf(p2, bf2f(a2.x), acc.x);
        acc.y = fmaf(p2, bf2f(a2.y), acc.y);
        acc.z = fmaf(p2, bf2f(a2.z), acc.z);
        acc.w = fmaf(p2, bf2f(a2.w), acc.w);
        acc.x = fmaf(p3, bf2f(a3.x), acc.x);
        acc.y = fmaf(p3, bf2f(a3.y), acc.y);
        acc.z = fmaf(p3, bf2f(a3.z), acc.z);
        acc.w = fmaf(p3, bf2f(a3.w), acc.w);
    }
    for (; kk < c; kk += 4) {
        int   j0 = sh.s_j[kk];
        float p0 = sh.s_p[h][kk];
        ushort4 a0 = *(const ushort4*)(hp + (size_t)j0 * HF);
        acc.x = fmaf(p0, bf2f(a0.x), acc.x);
        acc.y = fmaf(p0, bf2f(a0.y), acc.y);
        acc.z = fmaf(p0, bf2f(a0.z), acc.z);
        acc.w = fmaf(p0, bf2f(a0.w), acc.w);
    }
    *(float4*)&sh.s_red[w][4 * lane] = acc;
    __syncthreads();

    float tot = sh.s_red[0][tid] + sh.s_red[1][tid]
              + sh.s_red[2][tid] + sh.s_red[3][tid];
    float vv = tot * sh.s_inv[tid >> 6] + skipv + bv;
    vv = vv > 0.f ? vv : expm1f(vv);
    out[(size_t)i * HF + tid] = vv;
}

extern "C" void kernel_launch(void* const* d_in, const int* in_sizes, int n_in,
                              void* d_out, int out_size, void* d_ws, size_t ws_size,
                              hipStream_t stream) {
    const float*        x    = (const float*)d_in[0];
    const unsigned int* mask = (const unsigned int*)d_in[1];
    const float*        proj = (const float*)d_in[2];
    const float*        asrc = (const float*)d_in[3];
    const float*        atgt = (const float*)d_in[4];
    const float*        skw  = (const float*)d_in[5];
    const float*        bias = (const float*)d_in[6];
    float*              out  = (float*)d_out;

    char* ws = (char*)d_ws;
    ushort_t* h2b     = (ushort_t*)ws;                          // 2 MB
    float*    skip_ws = (float*)(ws + (2u << 20));              // 4 MB
    float*    src4    = (float*)(ws + (6u << 20));              // 64 KB
    float*    tgt4    = (float*)(ws + (6u << 20) + (64u << 10));// 64 KB
    ushort_t* bm      = (ushort_t*)(ws + (8u << 20));           // 2 MB

    hipLaunchKernelGGL(k01_fused, dim3(GEMM_BLOCKS + SCAN_BLOCKS), dim3(256),
                       0, stream,
                       x, proj, skw, asrc, atgt, mask,
                       h2b, skip_ws, src4, tgt4, bm);
    hipLaunchKernelGGL(k2_attn, dim3(NN), dim3(256), 0, stream,
                       bm, h2b, skip_ws, src4, tgt4, bias, out);
}